// Round 11
// baseline (46.243 us; speedup 1.0000x reference)
//
#include <hip/hip_runtime.h>
#include <math.h>

#define DIM 256
#define NLAYERS 64

typedef __attribute__((ext_vector_type(8))) short short8;
typedef __attribute__((ext_vector_type(4))) float f32x4;

// ---------- helpers ----------
__device__ __forceinline__ float dpp_shl1_zero(float v) {
    int r = __builtin_amdgcn_update_dpp(0, __float_as_int(v), 0x130, 0xF, 0xF, true);
    return __int_as_float(r);
}
__device__ __forceinline__ float dpp_shr1_keep(float oldv, float v) {
    int r = __builtin_amdgcn_update_dpp(__float_as_int(oldv), __float_as_int(v), 0x138, 0xF, 0xF, false);
    return __int_as_float(r);
}
// f32 -> bf16 bits, RNE (cold path: build_m only).
__device__ __forceinline__ unsigned short f2bf(float f) {
    unsigned u = __float_as_uint(f);
    u += 0x7FFFu + ((u >> 16) & 1u);
    return (unsigned short)(u >> 16);
}
// packed f32x2 -> bf16x2 (RNE), single VALU op (no builtin on gfx950, m240).
__device__ __forceinline__ unsigned cvtpk_bf16(float a, float b) {
    unsigned r;
    asm("v_cvt_pk_bf16_f32 %0, %1, %2" : "=v"(r) : "v"(a), "v"(b));
    return r;
}

// ---------- kernel 1: build M in MFMA-fragment order (bf16) ----------
// 64 blocks x 256 threads (4 waves x 1 identity row); ~256 ds_read_b128/CU.
// Fast trig via __sinf/__cosf (~1e-6 err << bf16 quantization).
// Row k of M stored at fragment granule:
//   bfrag[(((col>>4)*8 + (k>>5))*64 + ((k>>3)&3)*16 + (col&15))*8 + (k&7)]
__global__ __launch_bounds__(256)
void build_m_kernel(const float* __restrict__ theta, unsigned short* __restrict__ bfrag) {
    __shared__ float tbl[NLAYERS * DIM];   // 64 KB: [(l*128+p)*2 + {c,s}]
    const int tid = threadIdx.x;
    #pragma unroll 4
    for (int kk = 0; kk < 32; ++kk) {
        int idx = tid + 256 * kk;          // idx = l*128 + p
        int l = idx >> 7, p = idx & 127;
        float a = 2.0f * theta[idx];
        float s = __sinf(a), c = __cosf(a);
        if ((l & 1) && (p == 127)) { c = 1.0f; s = 0.0f; }   // odd-layer passthrough pair
        tbl[idx * 2 + 0] = c;
        tbl[idx * 2 + 1] = s;
    }
    __syncthreads();

    const int w = tid >> 6;
    const int t = tid & 63;
    const int row = blockIdx.x * 4 + w;    // 0..255

    float e[4];
    #pragma unroll
    for (int j = 0; j < 4; ++j) e[j] = (4 * t + j == row) ? 1.0f : 0.0f;

    const float4* tbl4 = (const float4*)tbl;
    #pragma unroll 2
    for (int l = 0; l < NLAYERS; l += 2) {
        float4 cs = tbl4[(l << 6) + t];
        {
            float a0 = e[0], a1 = e[1], a2 = e[2], a3 = e[3];
            e[0] = cs.x * a0 + cs.y * a1;
            e[1] = cs.y * a0 - cs.x * a1;
            e[2] = cs.z * a2 + cs.w * a3;
            e[3] = cs.w * a2 - cs.z * a3;
        }
        float4 cs1 = tbl4[((l + 1) << 6) + t];
        {
            float a1 = e[1], a2 = e[2], a3 = e[3];
            float n1 = cs1.x * a1 + cs1.y * a2;
            float n2 = cs1.y * a1 - cs1.x * a2;
            float xjn = dpp_shl1_zero(e[0]);
            float n3  = cs1.z * a3 + cs1.w * xjn;
            float snd = cs1.w * a3 - cs1.z * xjn;
            e[0] = dpp_shr1_keep(e[0], snd);
            e[1] = n1; e[2] = n2; e[3] = n3;
        }
    }

    const int kt = row >> 5, g8 = (row >> 3) & 3, ki = row & 7;
    #pragma unroll
    for (int j = 0; j < 4; ++j) {
        int col = 4 * t + j;
        bfrag[(((col >> 4) * 8 + kt) * 64 + g8 * 16 + (col & 15)) * 8 + ki] = f2bf(e[j]);
    }
}

// ---------- kernel 2: out = x @ M — barrier-free direct-load MFMA ----------
// 512 blocks x 512 threads (8 waves); wave w owns output cols [32w,32w+32).
// NO LDS, NO barriers: the MFMA A-fragment for lane (g=t>>4, l16=t&15) is
// x[row16+l16][kt*32+g*8 .. +8] — loaded DIRECTLY as 2 x f32x4 per kt and
// converted in-register (v_cvt_pk). The block's 8 waves re-read the same 16
// rows; L1/L2 serve 7/8 of those hits, HBM reads x exactly once. Rolling
// depth-2 prefetch on kt (16 f32 regs); total VGPR ~107 < 128 -> 2 blocks/CU
// (16 waves): 32 KB/CU outstanding sustains HBM supply rate with every wave
// free-running (no lockstep, no vmcnt(0) drains — compiler per-reg waits).
// B per-wave in regs (Bf[8][2], coalesced 16B/lane from fragment-ordered
// bfrag, L2-hot). k enumeration k = kt*32 + 8*(t>>4) + i identical for A and
// B (hw perm cancels; verified R7-R10). C/D: col=lane&15, row=(lane>>4)*4+reg
// [m89].
__global__ __launch_bounds__(512, 4)
void clements_gemm(const float* __restrict__ x,
                   const unsigned short* __restrict__ bfrag,
                   float* __restrict__ out) {
    const int tid = threadIdx.x;
    const int w   = tid >> 6;       // wave 0..7
    const int t   = tid & 63;
    const int l16 = t & 15;
    const int g   = t >> 4;         // 0..3
    const long rowbase = (long)blockIdx.x * 64;

    // --- B preload (coalesced 16B/lane from fragment-ordered bfrag)
    short8 Bf[8][2];
    {
        const short8* bp = (const short8*)bfrag;
        #pragma unroll
        for (int nt = 0; nt < 2; ++nt)
            #pragma unroll
            for (int kt = 0; kt < 8; ++kt)
                Bf[kt][nt] = bp[((w * 2 + nt) * 8 + kt) * 64 + t];
    }

    #pragma unroll
    for (int rt = 0; rt < 4; ++rt) {
        const float* xr = x + (rowbase + rt * 16 + l16) * 256 + g * 8;

        // rolling depth-2: load kt+1 while converting/MFMA-ing kt
        f32x4 f0a = *(const f32x4*)(xr + 0);
        f32x4 f0b = *(const f32x4*)(xr + 4);
        f32x4 a0 = {0.f, 0.f, 0.f, 0.f}, a1 = {0.f, 0.f, 0.f, 0.f};

        #pragma unroll
        for (int kt = 0; kt < 8; ++kt) {
            f32x4 f1a, f1b;
            if (kt < 7) {
                f1a = *(const f32x4*)(xr + (kt + 1) * 32);
                f1b = *(const f32x4*)(xr + (kt + 1) * 32 + 4);
            }
            union { short8 s; unsigned u[4]; } A;
            A.u[0] = cvtpk_bf16(f0a[0], f0a[1]);
            A.u[1] = cvtpk_bf16(f0a[2], f0a[3]);
            A.u[2] = cvtpk_bf16(f0b[0], f0b[1]);
            A.u[3] = cvtpk_bf16(f0b[2], f0b[3]);
            a0 = __builtin_amdgcn_mfma_f32_16x16x32_bf16(A.s, Bf[kt][0], a0, 0, 0, 0);
            a1 = __builtin_amdgcn_mfma_f32_16x16x32_bf16(A.s, Bf[kt][1], a1, 0, 0, 0);
            if (kt < 7) { f0a = f1a; f0b = f1b; }
        }

        float* o = out + (rowbase + rt * 16 + g * 4) * 256 + 32 * w + l16;
        #pragma unroll
        for (int j = 0; j < 4; ++j) {
            o[(long)j * 256 +  0] = a0[j];
            o[(long)j * 256 + 16] = a1[j];
        }
    }
}

// ---------- fallback: verified R1 direct kernel (ws too small) ----------
__global__ __launch_bounds__(1024, 4)
void clements_direct(const float* __restrict__ x,
                     const float* __restrict__ theta,
                     float* __restrict__ out) {
    __shared__ float tbl[NLAYERS * DIM];
    const int tid = threadIdx.x;
    #pragma unroll
    for (int k = 0; k < 8; ++k) {
        int idx = tid + 1024 * k;
        int l = idx >> 7;
        int p = idx & 127;
        float s, c;
        sincosf(2.0f * theta[idx], &s, &c);
        if ((l & 1) && (p == 127)) { c = 1.0f; s = 0.0f; }
        tbl[idx * 2 + 0] = c;
        tbl[idx * 2 + 1] = s;
    }
    __syncthreads();
    const int w = tid >> 6;
    const int t = tid & 63;
    const long base = ((long)blockIdx.x * 16 + w) * 8;
    float e[8][4];
    #pragma unroll
    for (int r = 0; r < 8; ++r) {
        float4 v = ((const float4*)(x + (base + r) * (long)DIM))[t];
        e[r][0] = v.x; e[r][1] = v.y; e[r][2] = v.z; e[r][3] = v.w;
    }
    const float4* tbl4 = (const float4*)tbl;
    #pragma unroll 2
    for (int l = 0; l < NLAYERS; l += 2) {
        float4 cs = tbl4[(l << 6) + t];
        #pragma unroll
        for (int r = 0; r < 8; ++r) {
            float a0 = e[r][0], a1 = e[r][1], a2 = e[r][2], a3 = e[r][3];
            e[r][0] = cs.x * a0 + cs.y * a1;
            e[r][1] = cs.y * a0 - cs.x * a1;
            e[r][2] = cs.z * a2 + cs.w * a3;
            e[r][3] = cs.w * a2 - cs.z * a3;
        }
        float4 cs1 = tbl4[((l + 1) << 6) + t];
        #pragma unroll
        for (int r = 0; r < 8; ++r) {
            float a1 = e[r][1], a2 = e[r][2], a3 = e[r][3];
            float n1 = cs1.x * a1 + cs1.y * a2;
            float n2 = cs1.y * a1 - cs1.x * a2;
            float xjn = dpp_shl1_zero(e[r][0]);
            float n3  = cs1.z * a3 + cs1.w * xjn;
            float snd = cs1.w * a3 - cs1.z * xjn;
            e[r][0] = dpp_shr1_keep(e[r][0], snd);
            e[r][1] = n1; e[r][2] = n2; e[r][3] = n3;
        }
    }
    #pragma unroll
    for (int r = 0; r < 8; ++r) {
        float4 v;
        v.x = e[r][0]; v.y = e[r][1]; v.z = e[r][2]; v.w = e[r][3];
        ((float4*)(out + (base + r) * (long)DIM))[t] = v;
    }
}

extern "C" void kernel_launch(void* const* d_in, const int* in_sizes, int n_in,
                              void* d_out, int out_size, void* d_ws, size_t ws_size,
                              hipStream_t stream) {
    const float* x     = (const float*)d_in[0];
    const float* theta = (const float*)d_in[1];
    float* out = (float*)d_out;

    const size_t need = (size_t)DIM * DIM * sizeof(unsigned short);  // bfrag, 128 KB
    if (ws_size >= need) {
        unsigned short* bfrag = (unsigned short*)d_ws;
        hipLaunchKernelGGL(build_m_kernel, dim3(64),  dim3(256), 0, stream, theta, bfrag);
        hipLaunchKernelGGL(clements_gemm,  dim3(512), dim3(512), 0, stream, x, bfrag, out);
    } else {
        hipLaunchKernelGGL(clements_direct, dim3(256), dim3(1024), 0, stream, x, theta, out);
    }
}

// Round 12
// 39.863 us; speedup vs baseline: 1.1601x; 1.1601x over previous
//
#include <hip/hip_runtime.h>
#include <math.h>

#define DIM 256
#define NLAYERS 64

typedef __attribute__((ext_vector_type(8))) short short8;
typedef __attribute__((ext_vector_type(4))) float f32x4;

// ---------- helpers ----------
__device__ __forceinline__ float dpp_shl1_zero(float v) {
    int r = __builtin_amdgcn_update_dpp(0, __float_as_int(v), 0x130, 0xF, 0xF, true);
    return __int_as_float(r);
}
__device__ __forceinline__ float dpp_shr1_keep(float oldv, float v) {
    int r = __builtin_amdgcn_update_dpp(__float_as_int(oldv), __float_as_int(v), 0x138, 0xF, 0xF, false);
    return __int_as_float(r);
}
// f32 -> bf16 bits, RNE (cold path: build_m only).
__device__ __forceinline__ unsigned short f2bf(float f) {
    unsigned u = __float_as_uint(f);
    u += 0x7FFFu + ((u >> 16) & 1u);
    return (unsigned short)(u >> 16);
}
// packed f32x2 -> bf16x2 (RNE), single VALU op (no builtin on gfx950, m240).
__device__ __forceinline__ unsigned cvtpk_bf16(float a, float b) {
    unsigned r;
    asm("v_cvt_pk_bf16_f32 %0, %1, %2" : "=v"(r) : "v"(a), "v"(b));
    return r;
}

// ---------- kernel 1: build M in MFMA-fragment order (bf16) ----------
// 64 blocks x 256 threads (4 waves x 1 identity row). __sinf/__cosf trig.
// Row k of M stored at fragment granule:
//   bfrag[(((col>>4)*8 + (k>>5))*64 + ((k>>3)&3)*16 + (col&15))*8 + (k&7)]
__global__ __launch_bounds__(256)
void build_m_kernel(const float* __restrict__ theta, unsigned short* __restrict__ bfrag) {
    __shared__ float tbl[NLAYERS * DIM];   // 64 KB: [(l*128+p)*2 + {c,s}]
    const int tid = threadIdx.x;
    #pragma unroll 4
    for (int kk = 0; kk < 32; ++kk) {
        int idx = tid + 256 * kk;          // idx = l*128 + p
        int l = idx >> 7, p = idx & 127;
        float a = 2.0f * theta[idx];
        float s = __sinf(a), c = __cosf(a);
        if ((l & 1) && (p == 127)) { c = 1.0f; s = 0.0f; }   // odd-layer passthrough pair
        tbl[idx * 2 + 0] = c;
        tbl[idx * 2 + 1] = s;
    }
    __syncthreads();

    const int w = tid >> 6;
    const int t = tid & 63;
    const int row = blockIdx.x * 4 + w;    // 0..255

    float e[4];
    #pragma unroll
    for (int j = 0; j < 4; ++j) e[j] = (4 * t + j == row) ? 1.0f : 0.0f;

    const float4* tbl4 = (const float4*)tbl;
    #pragma unroll 2
    for (int l = 0; l < NLAYERS; l += 2) {
        float4 cs = tbl4[(l << 6) + t];
        {
            float a0 = e[0], a1 = e[1], a2 = e[2], a3 = e[3];
            e[0] = cs.x * a0 + cs.y * a1;
            e[1] = cs.y * a0 - cs.x * a1;
            e[2] = cs.z * a2 + cs.w * a3;
            e[3] = cs.w * a2 - cs.z * a3;
        }
        float4 cs1 = tbl4[((l + 1) << 6) + t];
        {
            float a1 = e[1], a2 = e[2], a3 = e[3];
            float n1 = cs1.x * a1 + cs1.y * a2;
            float n2 = cs1.y * a1 - cs1.x * a2;
            float xjn = dpp_shl1_zero(e[0]);
            float n3  = cs1.z * a3 + cs1.w * xjn;
            float snd = cs1.w * a3 - cs1.z * xjn;
            e[0] = dpp_shr1_keep(e[0], snd);
            e[1] = n1; e[2] = n2; e[3] = n3;
        }
    }

    const int kt = row >> 5, g8 = (row >> 3) & 3, ki = row & 7;
    #pragma unroll
    for (int j = 0; j < 4; ++j) {
        int col = 4 * t + j;
        bfrag[(((col >> 4) * 8 + kt) * 64 + g8 * 16 + (col & 15)) * 8 + ki] = f2bf(e[j]);
    }
}

// ---------- kernel 2: R10 GEMM body, x3 INTERNAL REPEAT (diagnostic round) --
// Identical structure/config to R10 (512 blocks x 512 thr, reg-staged bf16
// LDS fragments, depth-2 ping-pong, per-chunk lgkmcnt+s_barrier). The rep
// loop re-runs staging+compute on the SAME data (same output -> passes) to
// (a) lift this dispatch into the profiled top-5 with counters and
// (b) give a cold/warm HBM A/B (reps 2-3 are L3-fed).
// READOUT (pre-committed): VGPR>128/low-occ -> reg pressure; conflicts>0 ->
// swizzle bug; VALUBusy>50% -> staging VALU-bound; all-low & T3==3T1 ->
// latency structure; T3 == T1+2*smaller -> HBM-supply-bound.
__global__ __launch_bounds__(512, 4)
void clements_gemm(const float* __restrict__ x,
                   const unsigned short* __restrict__ bfrag,
                   float* __restrict__ out) {
    __shared__ unsigned short abf[2][4096];   // ping-pong, 2 x 8 KB

    const int tid = threadIdx.x;
    const int w   = tid >> 6;       // wave 0..7
    const int t   = tid & 63;
    const int l16 = t & 15;
    const int g   = t >> 4;         // 0..3
    const long rowbase = (long)blockIdx.x * 64;

    // staging map: thread -> (row in chunk, k-octet)
    const int sr = tid >> 5;        // 0..15
    const int so = tid & 31;        // 0..31
    const int wsw = (((so >> 2) * 1024) + ((so & 3) * 256) + (sr * 16)) ^ ((so & 7) << 4);
    const float* const xp = x + (rowbase + sr) * 256 + so * 8;

    f32x4 pa[2], pb[2];
#define LOADR(i) { pa[(i) & 1] = *(const f32x4*)(xp + (i) * 16 * 256);       \
                   pb[(i) & 1] = *(const f32x4*)(xp + (i) * 16 * 256 + 4); }
#define CVTW(i) { union { short8 s; unsigned u[4]; } h;                      \
        h.u[0] = cvtpk_bf16(pa[(i) & 1][0], pa[(i) & 1][1]);                 \
        h.u[1] = cvtpk_bf16(pa[(i) & 1][2], pa[(i) & 1][3]);                 \
        h.u[2] = cvtpk_bf16(pb[(i) & 1][0], pb[(i) & 1][1]);                 \
        h.u[3] = cvtpk_bf16(pb[(i) & 1][2], pb[(i) & 1][3]);                 \
        *(short8*)((char*)&abf[(i) & 1][0] + wsw) = h.s; }
#define BAR() { asm volatile("s_waitcnt lgkmcnt(0)" ::: "memory");           \
                __builtin_amdgcn_s_barrier();                                \
                __builtin_amdgcn_sched_barrier(0); }

    // --- B preload ONCE (so the probe doesn't triple B traffic)
    short8 Bf[8][2];
    {
        const short8* bp = (const short8*)bfrag;
        #pragma unroll
        for (int nt = 0; nt < 2; ++nt)
            #pragma unroll
            for (int kt = 0; kt < 8; ++kt)
                Bf[kt][nt] = bp[((w * 2 + nt) * 8 + kt) * 64 + t];
    }

    auto compute = [&](int i) {
        f32x4 a0 = {0.f,0.f,0.f,0.f}, a1 = {0.f,0.f,0.f,0.f};
        const char* rb = (const char*)&abf[i & 1][0];
        #pragma unroll
        for (int kt = 0; kt < 8; ++kt) {
            short8 A = *(const short8*)(rb +
                ((kt * 1024 + t * 16) ^ (((kt * 4 + g) & 7) << 4)));
            a0 = __builtin_amdgcn_mfma_f32_16x16x32_bf16(A, Bf[kt][0], a0, 0, 0, 0);
            a1 = __builtin_amdgcn_mfma_f32_16x16x32_bf16(A, Bf[kt][1], a1, 0, 0, 0);
        }
        float* o = out + (rowbase + i * 16 + g * 4) * 256 + 32 * w + l16;
        #pragma unroll
        for (int j = 0; j < 4; ++j) {
            o[(long)j * 256 +  0] = a0[j];
            o[(long)j * 256 + 16] = a1[j];
        }
    };

    #pragma unroll 1
    for (int rep = 0; rep < 3; ++rep) {
        // prologue: 2 chunks of loads in flight, stage chunk 0
        LOADR(0) LOADR(1)
        CVTW(0)
        BAR()
        // main pipeline: LOAD(c+2) | compute(c) | CVTW(c+1) | BAR
        #pragma unroll
        for (int c = 0; c < 4; ++c) {
            if (c + 2 < 4) LOADR(c + 2)
            compute(c);
            if (c + 1 < 4) {
                CVTW(c + 1)
                BAR()
            }
        }
        // rep boundary: next rep's CVTW(0) writes abf[0] while stragglers may
        // still read abf[1] in compute(3) -> distinct buffers, race-free; the
        // BAR after next CVTW(0) orders abf[1] reuse. No extra barrier needed.
    }
#undef LOADR
#undef CVTW
#undef BAR
}

// ---------- fallback: verified R1 direct kernel (ws too small) ----------
__global__ __launch_bounds__(1024, 4)
void clements_direct(const float* __restrict__ x,
                     const float* __restrict__ theta,
                     float* __restrict__ out) {
    __shared__ float tbl[NLAYERS * DIM];
    const int tid = threadIdx.x;
    #pragma unroll
    for (int k = 0; k < 8; ++k) {
        int idx = tid + 1024 * k;
        int l = idx >> 7;
        int p = idx & 127;
        float s, c;
        sincosf(2.0f * theta[idx], &s, &c);
        if ((l & 1) && (p == 127)) { c = 1.0f; s = 0.0f; }
        tbl[idx * 2 + 0] = c;
        tbl[idx * 2 + 1] = s;
    }
    __syncthreads();
    const int w = tid >> 6;
    const int t = tid & 63;
    const long base = ((long)blockIdx.x * 16 + w) * 8;
    float e[8][4];
    #pragma unroll
    for (int r = 0; r < 8; ++r) {
        float4 v = ((const float4*)(x + (base + r) * (long)DIM))[t];
        e[r][0] = v.x; e[r][1] = v.y; e[r][2] = v.z; e[r][3] = v.w;
    }
    const float4* tbl4 = (const float4*)tbl;
    #pragma unroll 2
    for (int l = 0; l < NLAYERS; l += 2) {
        float4 cs = tbl4[(l << 6) + t];
        #pragma unroll
        for (int r = 0; r < 8; ++r) {
            float a0 = e[r][0], a1 = e[r][1], a2 = e[r][2], a3 = e[r][3];
            e[r][0] = cs.x * a0 + cs.y * a1;
            e[r][1] = cs.y * a0 - cs.x * a1;
            e[r][2] = cs.z * a2 + cs.w * a3;
            e[r][3] = cs.w * a2 - cs.z * a3;
        }
        float4 cs1 = tbl4[((l + 1) << 6) + t];
        #pragma unroll
        for (int r = 0; r < 8; ++r) {
            float a1 = e[r][1], a2 = e[r][2], a3 = e[r][3];
            float n1 = cs1.x * a1 + cs1.y * a2;
            float n2 = cs1.y * a1 - cs1.x * a2;
            float xjn = dpp_shl1_zero(e[r][0]);
            float n3  = cs1.z * a3 + cs1.w * xjn;
            float snd = cs1.w * a3 - cs1.z * xjn;
            e[r][0] = dpp_shr1_keep(e[r][0], snd);
            e[r][1] = n1; e[r][2] = n2; e[r][3] = n3;
        }
    }
    #pragma unroll
    for (int r = 0; r < 8; ++r) {
        float4 v;
        v.x = e[r][0]; v.y = e[r][1]; v.z = e[r][2]; v.w = e[r][3];
        ((float4*)(out + (base + r) * (long)DIM))[t] = v;
    }
}

extern "C" void kernel_launch(void* const* d_in, const int* in_sizes, int n_in,
                              void* d_out, int out_size, void* d_ws, size_t ws_size,
                              hipStream_t stream) {
    const float* x     = (const float*)d_in[0];
    const float* theta = (const float*)d_in[1];
    float* out = (float*)d_out;

    const size_t need = (size_t)DIM * DIM * sizeof(unsigned short);  // bfrag, 128 KB
    if (ws_size >= need) {
        unsigned short* bfrag = (unsigned short*)d_ws;
        hipLaunchKernelGGL(build_m_kernel, dim3(64),  dim3(256), 0, stream, theta, bfrag);
        hipLaunchKernelGGL(clements_gemm,  dim3(512), dim3(512), 0, stream, x, bfrag, out);
    } else {
        hipLaunchKernelGGL(clements_direct, dim3(256), dim3(1024), 0, stream, x, theta, out);
    }
}

// Round 13
// 27.408 us; speedup vs baseline: 1.6872x; 1.4544x over previous
//
#include <hip/hip_runtime.h>
#include <math.h>

#define DIM 256
#define NLAYERS 64

typedef __attribute__((ext_vector_type(8))) short short8;
typedef __attribute__((ext_vector_type(4))) float f32x4;

// ---------- helpers ----------
__device__ __forceinline__ float dpp_shl1_zero(float v) {
    int r = __builtin_amdgcn_update_dpp(0, __float_as_int(v), 0x130, 0xF, 0xF, true);
    return __int_as_float(r);
}
__device__ __forceinline__ float dpp_shr1_keep(float oldv, float v) {
    int r = __builtin_amdgcn_update_dpp(__float_as_int(oldv), __float_as_int(v), 0x138, 0xF, 0xF, false);
    return __int_as_float(r);
}
// f32 -> bf16 bits, RNE (cold path: build_m only).
__device__ __forceinline__ unsigned short f2bf(float f) {
    unsigned u = __float_as_uint(f);
    u += 0x7FFFu + ((u >> 16) & 1u);
    return (unsigned short)(u >> 16);
}
// packed f32x2 -> bf16x2 (RNE), single VALU op (no builtin on gfx950, m240).
__device__ __forceinline__ unsigned cvtpk_bf16(float a, float b) {
    unsigned r;
    asm("v_cvt_pk_bf16_f32 %0, %1, %2" : "=v"(r) : "v"(a), "v"(b));
    return r;
}

// ---------- kernel 1: build M in MFMA-fragment order (bf16) ----------
// 64 blocks x 256 threads (4 waves x 1 identity row). __sinf/__cosf trig.
// Row k of M stored at fragment granule:
//   bfrag[(((col>>4)*8 + (k>>5))*64 + ((k>>3)&3)*16 + (col&15))*8 + (k&7)]
__global__ __launch_bounds__(256)
void build_m_kernel(const float* __restrict__ theta, unsigned short* __restrict__ bfrag) {
    __shared__ float tbl[NLAYERS * DIM];   // 64 KB: [(l*128+p)*2 + {c,s}]
    const int tid = threadIdx.x;
    #pragma unroll 4
    for (int kk = 0; kk < 32; ++kk) {
        int idx = tid + 256 * kk;          // idx = l*128 + p
        int l = idx >> 7, p = idx & 127;
        float a = 2.0f * theta[idx];
        float s = __sinf(a), c = __cosf(a);
        if ((l & 1) && (p == 127)) { c = 1.0f; s = 0.0f; }   // odd-layer passthrough pair
        tbl[idx * 2 + 0] = c;
        tbl[idx * 2 + 1] = s;
    }
    __syncthreads();

    const int w = tid >> 6;
    const int t = tid & 63;
    const int row = blockIdx.x * 4 + w;    // 0..255

    float e[4];
    #pragma unroll
    for (int j = 0; j < 4; ++j) e[j] = (4 * t + j == row) ? 1.0f : 0.0f;

    const float4* tbl4 = (const float4*)tbl;
    #pragma unroll 2
    for (int l = 0; l < NLAYERS; l += 2) {
        float4 cs = tbl4[(l << 6) + t];
        {
            float a0 = e[0], a1 = e[1], a2 = e[2], a3 = e[3];
            e[0] = cs.x * a0 + cs.y * a1;
            e[1] = cs.y * a0 - cs.x * a1;
            e[2] = cs.z * a2 + cs.w * a3;
            e[3] = cs.w * a2 - cs.z * a3;
        }
        float4 cs1 = tbl4[((l + 1) << 6) + t];
        {
            float a1 = e[1], a2 = e[2], a3 = e[3];
            float n1 = cs1.x * a1 + cs1.y * a2;
            float n2 = cs1.y * a1 - cs1.x * a2;
            float xjn = dpp_shl1_zero(e[0]);
            float n3  = cs1.z * a3 + cs1.w * xjn;
            float snd = cs1.w * a3 - cs1.z * xjn;
            e[0] = dpp_shr1_keep(e[0], snd);
            e[1] = n1; e[2] = n2; e[3] = n3;
        }
    }

    const int kt = row >> 5, g8 = (row >> 3) & 3, ki = row & 7;
    #pragma unroll
    for (int j = 0; j < 4; ++j) {
        int col = 4 * t + j;
        bfrag[(((col >> 4) * 8 + kt) * 64 + g8 * 16 + (col & 15)) * 8 + ki] = f2bf(e[j]);
    }
}

// ---------- kernel 2: out = x @ M — small-block (4-wave) decoupled pipeline --
// R12 probe verdict: VGPR 64 / conflicts 0 / VALU 4.5% / 42% BW -> the 8-wave
// block-wide barrier lockstep (2 groups/CU) was the limiter. Fix: 1024 blocks
// x 256 thr (4 waves); block = 64 rows x 128 cols (bid&1 = col half; pairs
// share rows -> 2nd read L3-served, HBM unchanged). Per CU: 4 independent
// barrier groups, 16 waves -> barrier stalls of one block covered by 3 others.
// Same verified machinery as R10/R12: fragment-order LDS (granule byte =
// (kt*1024 + g*256 + sr*16) ^ ((o&7)<<4), o=k-octet; 0 conflicts measured),
// reg-stage + v_cvt_pk once, depth-2 ping-pong (pa/pb[2][2] = 32 VGPR),
// compiler per-reg waitcnts (no vmcnt drains), per-chunk lgkmcnt+s_barrier.
// Thread (o=tid&31, sr2=tid>>5) stages rows sr2 and sr2+8 of each 16-row
// chunk (2x dwordx4-pair loads, 2 granule writes at +0/+128 bytes).
// k enum k = kt*32 + 8*(t>>4) + i identical A/B (hw perm cancels).
// C/D: col=lane&15, row=(lane>>4)*4+reg [m89].
__global__ __launch_bounds__(256, 4)
void clements_gemm(const float* __restrict__ x,
                   const unsigned short* __restrict__ bfrag,
                   float* __restrict__ out) {
    __shared__ unsigned short abf[2][4096];   // ping-pong, 2 x 8 KB

    const int tid = threadIdx.x;
    const int w   = tid >> 6;       // wave 0..3
    const int t   = tid & 63;
    const int l16 = t & 15;
    const int g   = t >> 4;         // 0..3
    const int colbase = (blockIdx.x & 1) * 128 + w * 32;
    const long rowbase = (long)(blockIdx.x >> 1) * 64;

    // staging map: thread -> (k-octet o, rows sr2 / sr2+8)
    const int o   = tid & 31;
    const int sr2 = tid >> 5;       // 0..7
    const int wsw0 = (((o >> 2) * 1024) + ((o & 3) * 256) + (sr2 * 16)) ^ ((o & 7) << 4);
    const int wsw1 = wsw0 + 128;    // row sr2+8 (bit7 disjoint from the <<4 swizzle)
    const float* const xp = x + (rowbase + sr2) * 256 + o * 8;

    f32x4 pa[2][2], pb[2][2];       // [buf][row-half] = 32 VGPR
#define LOADR(i) { \
    pa[(i) & 1][0] = *(const f32x4*)(xp + (i) * 16 * 256); \
    pb[(i) & 1][0] = *(const f32x4*)(xp + (i) * 16 * 256 + 4); \
    pa[(i) & 1][1] = *(const f32x4*)(xp + (i) * 16 * 256 + 8 * 256); \
    pb[(i) & 1][1] = *(const f32x4*)(xp + (i) * 16 * 256 + 8 * 256 + 4); }
#define CVTW(i) { \
    union { short8 s; unsigned u[4]; } h0, h1; \
    h0.u[0] = cvtpk_bf16(pa[(i) & 1][0][0], pa[(i) & 1][0][1]); \
    h0.u[1] = cvtpk_bf16(pa[(i) & 1][0][2], pa[(i) & 1][0][3]); \
    h0.u[2] = cvtpk_bf16(pb[(i) & 1][0][0], pb[(i) & 1][0][1]); \
    h0.u[3] = cvtpk_bf16(pb[(i) & 1][0][2], pb[(i) & 1][0][3]); \
    h1.u[0] = cvtpk_bf16(pa[(i) & 1][1][0], pa[(i) & 1][1][1]); \
    h1.u[1] = cvtpk_bf16(pa[(i) & 1][1][2], pa[(i) & 1][1][3]); \
    h1.u[2] = cvtpk_bf16(pb[(i) & 1][1][0], pb[(i) & 1][1][1]); \
    h1.u[3] = cvtpk_bf16(pb[(i) & 1][1][2], pb[(i) & 1][1][3]); \
    *(short8*)((char*)&abf[(i) & 1][0] + wsw0) = h0.s; \
    *(short8*)((char*)&abf[(i) & 1][0] + wsw1) = h1.s; }
#define BAR() { asm volatile("s_waitcnt lgkmcnt(0)" ::: "memory"); \
                __builtin_amdgcn_s_barrier(); \
                __builtin_amdgcn_sched_barrier(0); }

    // --- x loads first (HBM = long pole), then B (L2-hot)
    LOADR(0) LOADR(1)

    short8 Bf[8][2];
    {
        const short8* bp = (const short8*)bfrag;
        const int cb16 = (blockIdx.x & 1) * 8 + w * 2;   // col/16 base
        #pragma unroll
        for (int nt = 0; nt < 2; ++nt)
            #pragma unroll
            for (int kt = 0; kt < 8; ++kt)
                Bf[kt][nt] = bp[((cb16 + nt) * 8 + kt) * 64 + t];
    }

    CVTW(0)
    BAR()

    auto compute = [&](int i) {
        f32x4 a0 = {0.f,0.f,0.f,0.f}, a1 = {0.f,0.f,0.f,0.f};
        const char* rb = (const char*)&abf[i & 1][0];
        #pragma unroll
        for (int kt = 0; kt < 8; ++kt) {
            short8 A = *(const short8*)(rb +
                ((kt * 1024 + t * 16) ^ (((kt * 4 + g) & 7) << 4)));
            a0 = __builtin_amdgcn_mfma_f32_16x16x32_bf16(A, Bf[kt][0], a0, 0, 0, 0);
            a1 = __builtin_amdgcn_mfma_f32_16x16x32_bf16(A, Bf[kt][1], a1, 0, 0, 0);
        }
        float* op = out + (rowbase + i * 16 + g * 4) * 256 + colbase + l16;
        #pragma unroll
        for (int j = 0; j < 4; ++j) {
            op[(long)j * 256 +  0] = a0[j];
            op[(long)j * 256 + 16] = a1[j];
        }
    };

    // --- main pipeline: LOAD(c+2) | compute(c) | CVTW(c+1) | BAR
    #pragma unroll
    for (int c = 0; c < 4; ++c) {
        if (c + 2 < 4) LOADR(c + 2)
        compute(c);
        if (c + 1 < 4) {
            CVTW(c + 1)
            BAR()
        }
    }
#undef LOADR
#undef CVTW
#undef BAR
}

// ---------- fallback: verified R1 direct kernel (ws too small) ----------
__global__ __launch_bounds__(1024, 4)
void clements_direct(const float* __restrict__ x,
                     const float* __restrict__ theta,
                     float* __restrict__ out) {
    __shared__ float tbl[NLAYERS * DIM];
    const int tid = threadIdx.x;
    #pragma unroll
    for (int k = 0; k < 8; ++k) {
        int idx = tid + 1024 * k;
        int l = idx >> 7;
        int p = idx & 127;
        float s, c;
        sincosf(2.0f * theta[idx], &s, &c);
        if ((l & 1) && (p == 127)) { c = 1.0f; s = 0.0f; }
        tbl[idx * 2 + 0] = c;
        tbl[idx * 2 + 1] = s;
    }
    __syncthreads();
    const int w = tid >> 6;
    const int t = tid & 63;
    const long base = ((long)blockIdx.x * 16 + w) * 8;
    float e[8][4];
    #pragma unroll
    for (int r = 0; r < 8; ++r) {
        float4 v = ((const float4*)(x + (base + r) * (long)DIM))[t];
        e[r][0] = v.x; e[r][1] = v.y; e[r][2] = v.z; e[r][3] = v.w;
    }
    const float4* tbl4 = (const float4*)tbl;
    #pragma unroll 2
    for (int l = 0; l < NLAYERS; l += 2) {
        float4 cs = tbl4[(l << 6) + t];
        #pragma unroll
        for (int r = 0; r < 8; ++r) {
            float a0 = e[r][0], a1 = e[r][1], a2 = e[r][2], a3 = e[r][3];
            e[r][0] = cs.x * a0 + cs.y * a1;
            e[r][1] = cs.y * a0 - cs.x * a1;
            e[r][2] = cs.z * a2 + cs.w * a3;
            e[r][3] = cs.w * a2 - cs.z * a3;
        }
        float4 cs1 = tbl4[((l + 1) << 6) + t];
        #pragma unroll
        for (int r = 0; r < 8; ++r) {
            float a1 = e[r][1], a2 = e[r][2], a3 = e[r][3];
            float n1 = cs1.x * a1 + cs1.y * a2;
            float n2 = cs1.y * a1 - cs1.x * a2;
            float xjn = dpp_shl1_zero(e[r][0]);
            float n3  = cs1.z * a3 + cs1.w * xjn;
            float snd = cs1.w * a3 - cs1.z * xjn;
            e[r][0] = dpp_shr1_keep(e[r][0], snd);
            e[r][1] = n1; e[r][2] = n2; e[r][3] = n3;
        }
    }
    #pragma unroll
    for (int r = 0; r < 8; ++r) {
        float4 v;
        v.x = e[r][0]; v.y = e[r][1]; v.z = e[r][2]; v.w = e[r][3];
        ((float4*)(out + (base + r) * (long)DIM))[t] = v;
    }
}

extern "C" void kernel_launch(void* const* d_in, const int* in_sizes, int n_in,
                              void* d_out, int out_size, void* d_ws, size_t ws_size,
                              hipStream_t stream) {
    const float* x     = (const float*)d_in[0];
    const float* theta = (const float*)d_in[1];
    float* out = (float*)d_out;

    const size_t need = (size_t)DIM * DIM * sizeof(unsigned short);  // bfrag, 128 KB
    if (ws_size >= need) {
        unsigned short* bfrag = (unsigned short*)d_ws;
        hipLaunchKernelGGL(build_m_kernel, dim3(64),   dim3(256), 0, stream, theta, bfrag);
        hipLaunchKernelGGL(clements_gemm,  dim3(1024), dim3(256), 0, stream, x, bfrag, out);
    } else {
        hipLaunchKernelGGL(clements_direct, dim3(256), dim3(1024), 0, stream, x, theta, out);
    }
}

// Round 14
// 24.640 us; speedup vs baseline: 1.8768x; 1.1124x over previous
//
#include <hip/hip_runtime.h>
#include <math.h>

#define DIM 256
#define NLAYERS 64

typedef __attribute__((ext_vector_type(8))) short short8;
typedef __attribute__((ext_vector_type(4))) float f32x4;

// ---------- helpers ----------
__device__ __forceinline__ float dpp_shl1_zero(float v) {
    int r = __builtin_amdgcn_update_dpp(0, __float_as_int(v), 0x130, 0xF, 0xF, true);
    return __int_as_float(r);
}
__device__ __forceinline__ float dpp_shr1_keep(float oldv, float v) {
    int r = __builtin_amdgcn_update_dpp(__float_as_int(oldv), __float_as_int(v), 0x138, 0xF, 0xF, false);
    return __int_as_float(r);
}
// f32 -> bf16 bits, RNE (cold path: build_m only).
__device__ __forceinline__ unsigned short f2bf(float f) {
    unsigned u = __float_as_uint(f);
    u += 0x7FFFu + ((u >> 16) & 1u);
    return (unsigned short)(u >> 16);
}
// packed f32x2 -> bf16x2 (RNE), single VALU op (no builtin on gfx950, m240).
__device__ __forceinline__ unsigned cvtpk_bf16(float a, float b) {
    unsigned r;
    asm("v_cvt_pk_bf16_f32 %0, %1, %2" : "=v"(r) : "v"(a), "v"(b));
    return r;
}

// ---------- kernel 1: build M in MFMA-fragment order (bf16) ----------
// 64 blocks x 256 threads (4 waves x 1 identity row). __sinf/__cosf trig.
// Row k of M stored at fragment granule:
//   bfrag[(((col>>4)*8 + (k>>5))*64 + ((k>>3)&3)*16 + (col&15))*8 + (k&7)]
__global__ __launch_bounds__(256)
void build_m_kernel(const float* __restrict__ theta, unsigned short* __restrict__ bfrag) {
    __shared__ float tbl[NLAYERS * DIM];   // 64 KB: [(l*128+p)*2 + {c,s}]
    const int tid = threadIdx.x;
    #pragma unroll 4
    for (int kk = 0; kk < 32; ++kk) {
        int idx = tid + 256 * kk;          // idx = l*128 + p
        int l = idx >> 7, p = idx & 127;
        float a = 2.0f * theta[idx];
        float s = __sinf(a), c = __cosf(a);
        if ((l & 1) && (p == 127)) { c = 1.0f; s = 0.0f; }   // odd-layer passthrough pair
        tbl[idx * 2 + 0] = c;
        tbl[idx * 2 + 1] = s;
    }
    __syncthreads();

    const int w = tid >> 6;
    const int t = tid & 63;
    const int row = blockIdx.x * 4 + w;    // 0..255

    float e[4];
    #pragma unroll
    for (int j = 0; j < 4; ++j) e[j] = (4 * t + j == row) ? 1.0f : 0.0f;

    const float4* tbl4 = (const float4*)tbl;
    #pragma unroll 2
    for (int l = 0; l < NLAYERS; l += 2) {
        float4 cs = tbl4[(l << 6) + t];
        {
            float a0 = e[0], a1 = e[1], a2 = e[2], a3 = e[3];
            e[0] = cs.x * a0 + cs.y * a1;
            e[1] = cs.y * a0 - cs.x * a1;
            e[2] = cs.z * a2 + cs.w * a3;
            e[3] = cs.w * a2 - cs.z * a3;
        }
        float4 cs1 = tbl4[((l + 1) << 6) + t];
        {
            float a1 = e[1], a2 = e[2], a3 = e[3];
            float n1 = cs1.x * a1 + cs1.y * a2;
            float n2 = cs1.y * a1 - cs1.x * a2;
            float xjn = dpp_shl1_zero(e[0]);
            float n3  = cs1.z * a3 + cs1.w * xjn;
            float snd = cs1.w * a3 - cs1.z * xjn;
            e[0] = dpp_shr1_keep(e[0], snd);
            e[1] = n1; e[2] = n2; e[3] = n3;
        }
    }

    const int kt = row >> 5, g8 = (row >> 3) & 3, ki = row & 7;
    #pragma unroll
    for (int j = 0; j < 4; ++j) {
        int col = 4 * t + j;
        bfrag[(((col >> 4) * 8 + kt) * 64 + g8 * 16 + (col & 15)) * 8 + ki] = f2bf(e[j]);
    }
}

// ---------- kernel 2: out = x @ M — R10 machinery, 4 blocks/CU occupancy ----
// R12 probe: VGPR 64 / LDS 16KB / conflicts 0 -> FOUR blocks fit per CU, but
// grid 512 supplied only 2 (occupancy 23.6%) — grid size, not a resource, was
// the binding constraint of the whole R7-R12 family. Fix: 1024 blocks x 512
// thr, 32 rows/block (2 chunks), giving 4 independent barrier groups / 32
// waves per CU and 2x the cold in-flight loads. Everything else is verified
// R10 machinery: fragment-order LDS granule byte =
//   (kt*1024 + g*256 + sr*16) ^ ((o&7)<<4)  (0 conflicts measured),
// reg-stage + single v_cvt_pk, ping-pong 2x8KB, compiler per-reg waitcnts
// (no vmcnt drains), per-chunk lgkmcnt(0)+s_barrier+sched_barrier.
// B per-wave regs, L2-hot. k enum k = kt*32+8*(t>>4)+i identical A/B.
// C/D: col=lane&15, row=(lane>>4)*4+reg [m89].
__global__ __launch_bounds__(512, 4)
void clements_gemm(const float* __restrict__ x,
                   const unsigned short* __restrict__ bfrag,
                   float* __restrict__ out) {
    __shared__ unsigned short abf[2][4096];   // ping-pong, 2 x 8 KB

    const int tid = threadIdx.x;
    const int w   = tid >> 6;       // wave 0..7
    const int t   = tid & 63;
    const int l16 = t & 15;
    const int g   = t >> 4;         // 0..3
    const long rowbase = (long)blockIdx.x * 32;

    // staging map: thread -> (row in chunk, k-octet)
    const int sr = tid >> 5;        // 0..15
    const int so = tid & 31;        // 0..31
    const int wsw = (((so >> 2) * 1024) + ((so & 3) * 256) + (sr * 16)) ^ ((so & 7) << 4);
    const float* const xp = x + (rowbase + sr) * 256 + so * 8;

    f32x4 pa[2], pb[2];
#define LOADR(i) { pa[(i) & 1] = *(const f32x4*)(xp + (i) * 16 * 256);       \
                   pb[(i) & 1] = *(const f32x4*)(xp + (i) * 16 * 256 + 4); }
#define CVTW(i) { union { short8 s; unsigned u[4]; } h;                      \
        h.u[0] = cvtpk_bf16(pa[(i) & 1][0], pa[(i) & 1][1]);                 \
        h.u[1] = cvtpk_bf16(pa[(i) & 1][2], pa[(i) & 1][3]);                 \
        h.u[2] = cvtpk_bf16(pb[(i) & 1][0], pb[(i) & 1][1]);                 \
        h.u[3] = cvtpk_bf16(pb[(i) & 1][2], pb[(i) & 1][3]);                 \
        *(short8*)((char*)&abf[(i) & 1][0] + wsw) = h.s; }
#define BAR() { asm volatile("s_waitcnt lgkmcnt(0)" ::: "memory");           \
                __builtin_amdgcn_s_barrier();                                \
                __builtin_amdgcn_sched_barrier(0); }

    // --- x loads first (HBM, long pole), then B (L2-hot)
    LOADR(0) LOADR(1)

    short8 Bf[8][2];
    {
        const short8* bp = (const short8*)bfrag;
        #pragma unroll
        for (int nt = 0; nt < 2; ++nt)
            #pragma unroll
            for (int kt = 0; kt < 8; ++kt)
                Bf[kt][nt] = bp[((w * 2 + nt) * 8 + kt) * 64 + t];
    }

    CVTW(0)
    BAR()

    auto compute = [&](int i) {
        f32x4 a0 = {0.f,0.f,0.f,0.f}, a1 = {0.f,0.f,0.f,0.f};
        const char* rb = (const char*)&abf[i & 1][0];
        #pragma unroll
        for (int kt = 0; kt < 8; ++kt) {
            short8 A = *(const short8*)(rb +
                ((kt * 1024 + t * 16) ^ (((kt * 4 + g) & 7) << 4)));
            a0 = __builtin_amdgcn_mfma_f32_16x16x32_bf16(A, Bf[kt][0], a0, 0, 0, 0);
            a1 = __builtin_amdgcn_mfma_f32_16x16x32_bf16(A, Bf[kt][1], a1, 0, 0, 0);
        }
        float* o = out + (rowbase + i * 16 + g * 4) * 256 + 32 * w + l16;
        #pragma unroll
        for (int j = 0; j < 4; ++j) {
            o[(long)j * 256 +  0] = a0[j];
            o[(long)j * 256 + 16] = a1[j];
        }
    };

    // --- 2-chunk pipeline, 2 barriers total
    compute(0);
    CVTW(1)
    BAR()
    compute(1);
#undef LOADR
#undef CVTW
#undef BAR
}

// ---------- fallback: verified R1 direct kernel (ws too small) ----------
__global__ __launch_bounds__(1024, 4)
void clements_direct(const float* __restrict__ x,
                     const float* __restrict__ theta,
                     float* __restrict__ out) {
    __shared__ float tbl[NLAYERS * DIM];
    const int tid = threadIdx.x;
    #pragma unroll
    for (int k = 0; k < 8; ++k) {
        int idx = tid + 1024 * k;
        int l = idx >> 7;
        int p = idx & 127;
        float s, c;
        sincosf(2.0f * theta[idx], &s, &c);
        if ((l & 1) && (p == 127)) { c = 1.0f; s = 0.0f; }
        tbl[idx * 2 + 0] = c;
        tbl[idx * 2 + 1] = s;
    }
    __syncthreads();
    const int w = tid >> 6;
    const int t = tid & 63;
    const long base = ((long)blockIdx.x * 16 + w) * 8;
    float e[8][4];
    #pragma unroll
    for (int r = 0; r < 8; ++r) {
        float4 v = ((const float4*)(x + (base + r) * (long)DIM))[t];
        e[r][0] = v.x; e[r][1] = v.y; e[r][2] = v.z; e[r][3] = v.w;
    }
    const float4* tbl4 = (const float4*)tbl;
    #pragma unroll 2
    for (int l = 0; l < NLAYERS; l += 2) {
        float4 cs = tbl4[(l << 6) + t];
        #pragma unroll
        for (int r = 0; r < 8; ++r) {
            float a0 = e[r][0], a1 = e[r][1], a2 = e[r][2], a3 = e[r][3];
            e[r][0] = cs.x * a0 + cs.y * a1;
            e[r][1] = cs.y * a0 - cs.x * a1;
            e[r][2] = cs.z * a2 + cs.w * a3;
            e[r][3] = cs.w * a2 - cs.z * a3;
        }
        float4 cs1 = tbl4[((l + 1) << 6) + t];
        #pragma unroll
        for (int r = 0; r < 8; ++r) {
            float a1 = e[r][1], a2 = e[r][2], a3 = e[r][3];
            float n1 = cs1.x * a1 + cs1.y * a2;
            float n2 = cs1.y * a1 - cs1.x * a2;
            float xjn = dpp_shl1_zero(e[r][0]);
            float n3  = cs1.z * a3 + cs1.w * xjn;
            float snd = cs1.w * a3 - cs1.z * xjn;
            e[r][0] = dpp_shr1_keep(e[r][0], snd);
            e[r][1] = n1; e[r][2] = n2; e[r][3] = n3;
        }
    }
    #pragma unroll
    for (int r = 0; r < 8; ++r) {
        float4 v;
        v.x = e[r][0]; v.y = e[r][1]; v.z = e[r][2]; v.w = e[r][3];
        ((float4*)(out + (base + r) * (long)DIM))[t] = v;
    }
}

extern "C" void kernel_launch(void* const* d_in, const int* in_sizes, int n_in,
                              void* d_out, int out_size, void* d_ws, size_t ws_size,
                              hipStream_t stream) {
    const float* x     = (const float*)d_in[0];
    const float* theta = (const float*)d_in[1];
    float* out = (float*)d_out;

    const size_t need = (size_t)DIM * DIM * sizeof(unsigned short);  // bfrag, 128 KB
    if (ws_size >= need) {
        unsigned short* bfrag = (unsigned short*)d_ws;
        hipLaunchKernelGGL(build_m_kernel, dim3(64),   dim3(256), 0, stream, theta, bfrag);
        hipLaunchKernelGGL(clements_gemm,  dim3(1024), dim3(512), 0, stream, x, bfrag, out);
    } else {
        hipLaunchKernelGGL(clements_direct, dim3(256), dim3(1024), 0, stream, x, theta, out);
    }
}